// Round 2
// baseline (294.457 us; speedup 1.0000x reference)
//
#include <hip/hip_runtime.h>
#include <stdint.h>

// B=8, C=4, H=W=1024, PATCH=16, DOWN=4 -> L=4096, L2=256, K=256
// att_gt[b,c,l,m]*4096 = sum_k ind[b,c,l,k] * cnt[b,c,k,m]  (exact ints <= 4096)
// Strategy: fused prep (cls + cnt via LDS transpose) then i8 MFMA GEMM
// (M=4096,N=256,K=256 per (b,c)) with an LDS u16 relay so the MSE epilogue
// streams att perfectly linearly (float4, 1 KB/wave-instr) instead of in
// the strided 128-B C-fragment layout.

#define BDIM 256
#define GST 264   // u16 row stride: 528 B -> 4-row offset = 2112 B = bank+16,
                  // so khalf=0 and khalf=1 half-waves write disjoint banks.

typedef int v4i  __attribute__((ext_vector_type(4)));
typedef int v16i __attribute__((ext_vector_type(16)));

// ---------------------------------------------------------------------------
// K1: fused cls + cnt.
// Block = one 16-row x 256-col pixel region of one image (full ky set of
// 16 consecutive patches). grid.x = B * (H/16) * (W/256) = 2048.
//   read phase : 16 consecutive ints/lane, 16 lanes contiguous -> 256 B
//                segments, full cache-line utilization.
//   phase A    : cls[b][l][k] u8 in unfold layout, 1 KB contiguous per wave.
//   phase B    : 4x4 class counts -> cntT[b][c][m][km] (B-operand transposed).
// Also zeroes d_out (harness re-poisons it each launch).
// ---------------------------------------------------------------------------
__global__ __launch_bounds__(BDIM) void prep_kernel(
    const int* __restrict__ tgt, uint8_t* __restrict__ cls,
    uint8_t* __restrict__ cntT, float* __restrict__ dout) {
  __shared__ uint4 lcls[16][17];   // [row][wb], +1 pad
  const int t   = threadIdx.x;
  const int blk = blockIdx.x;
  if (blk == 0 && t == 0) *dout = 0.f;
  const int b  = blk >> 8;
  const int hr = (blk >> 2) & 63;   // h0 = hr*16
  const int wq = blk & 3;           // w0 = wq*256

  // --- read 16 target ints (one patch row), pack classes to 16 bytes ---
  {
    const int row = t >> 4, wb = t & 15;
    const int* p = tgt + ((size_t)b << 20) + ((size_t)((hr << 4) + row) << 10)
                 + (wq << 8) + (wb << 4);
    uint32_t o[4];
#pragma unroll
    for (int i = 0; i < 4; ++i) {
      int4 v = *(const int4*)(p + (i << 2));
      o[i] = (uint32_t)v.x | ((uint32_t)v.y << 8) |
             ((uint32_t)v.z << 16) | ((uint32_t)v.w << 24);
    }
    lcls[row][wb] = make_uint4(o[0], o[1], o[2], o[3]);
  }
  __syncthreads();

  // --- phase A: cls in unfold layout (transposed via LDS), coalesced ---
  {
    const int wb = t >> 4, ky = t & 15;
    const int l = (hr << 6) + (wq << 4) + wb;
    *(uint4*)(cls + ((size_t)b << 20) + ((size_t)l << 8) + (ky << 4)) =
        lcls[ky][wb];
  }

  // --- phase B: per pooled pixel (Y,X): count classes in its 4x4 block ---
  {
    const int py = t >> 6, px = t & 63;   // 4 x 64 pooled pixels in region
    uint32_t pc = 0;   // 4 packed u8 class counts (max 16 each)
#pragma unroll
    for (int dy = 0; dy < 4; ++dy) {
      uint32_t wv = ((const uint32_t*)&lcls[(py << 2) + dy][px >> 2])[px & 3];
#pragma unroll
      for (int s = 0; s < 32; s += 8)
        pc += 1u << (((wv >> s) & 3u) << 3);
    }
    const int Y = (hr << 2) + py, X = (wq << 6) + px;
    const int m  = ((Y >> 4) << 4) | (X >> 4);
    const int km = ((Y & 15) << 4) | (X & 15);
    size_t o = ((size_t)b << 18) | ((size_t)m << 8) | (size_t)km;
#pragma unroll
    for (int c = 0; c < 4; ++c)
      cntT[o + ((size_t)c << 16)] = (uint8_t)((pc >> (c << 3)) & 0xFFu);
  }
}

// ---------------------------------------------------------------------------
// K2: per (b,c): C[l][m] = sum_k ind[l][k]*cnt[k][m] via mfma_i32_32x32x32_i8,
// fused MSE vs att. Block = 64 l-rows x 256 m. 4 waves:
//   strip = wv&1 (which 32-l strip), mh = wv>>1 (which half of the 8 m-tiles).
// MFMA phase writes exact u16 att_gt*4096 into LDS gt[64][GST]; after one
// barrier the epilogue streams the block's 64 KB att tile with float4 loads
// (64 lanes x 16 B = one full 1 KB att row per instruction, sequential rows).
// A-frag layout: row = lane&31, k = (lane>>5)*16 + j (j = byte idx 0..15).
// B-frag layout: col = lane&31, k = (lane>>5)*16 + j.
// C/D layout:    col = lane&31, row = (reg&3) + 8*(reg>>2) + 4*(lane>>5).
// ---------------------------------------------------------------------------
__global__ __launch_bounds__(BDIM, 4) void gemm_kernel(
    const uint8_t* __restrict__ cls, const uint8_t* __restrict__ cntT,
    const float* __restrict__ att, float* __restrict__ dout) {
  __shared__ uint16_t gt[64][GST];   // 33792 B
  __shared__ float wsum[4];
  const int t    = threadIdx.x;
  const int wv   = t >> 6, lane = t & 63;
  const int bc   = blockIdx.y;              // 0..31 : b=bc>>2, c=bc&3
  const int b    = bc >> 2, c = bc & 3;
  const int lb   = blockIdx.x << 6;         // block's 64-l tile base
  const int strip = wv & 1;                 // which 32-l strip
  const int mh    = wv >> 1;                // which 4 m-tiles (mc = mh*4+i)
  const int lrow  = lane & 31;
  const int khalf = lane >> 5;

  // --- build the 8 A fragments (k-steps of 32), kept in VGPRs ---
  // classes are < 4 (2 bits), so byte==c  <=>  both low bits of (byte^c) zero.
  // EXACT per-byte test (the classic (x-0x01..)&~x&0x80.. SWAR has borrow
  // false-positives: byte i==0 && byte i+1==0x01 flags byte i+1 — measured
  // as the round-2 absmax 1.17e-2).
  const uint32_t crep = (uint32_t)c * 0x01010101u;
  v4i afr[8];
  const uint8_t* abase = cls + ((size_t)b << 20) +
                         ((size_t)(lb + (strip << 5) + lrow) << 8) +
                         (khalf << 4);
#pragma unroll
  for (int kk = 0; kk < 8; ++kk) {
    uint4 raw = *(const uint4*)(abase + (kk << 5));
    uint32_t r[4] = {raw.x, raw.y, raw.z, raw.w};
    v4i a;
#pragma unroll
    for (int i = 0; i < 4; ++i) {
      uint32_t x = r[i] ^ crep;                        // 0 where byte==c
      uint32_t nz = (x | (x >> 1)) & 0x01010101u;      // 1 where byte!=c
      a[i] = (int)(nz ^ 0x01010101u);                  // 1 where byte==c
    }
    afr[kk] = a;
  }

  const uint8_t* bbase = cntT + ((size_t)bc << 16) + (khalf << 4);

#pragma unroll 1
  for (int i = 0; i < 4; ++i) {
    const int mc = (mh << 2) + i;
    v16i acc = {0,0,0,0,0,0,0,0,0,0,0,0,0,0,0,0};
    const uint8_t* bb = bbase + ((size_t)((mc << 5) + lrow) << 8);
#pragma unroll
    for (int kk = 0; kk < 8; ++kk) {
      uint4 raw = *(const uint4*)(bb + (kk << 5));
      v4i bfr;
      bfr[0] = (int)raw.x; bfr[1] = (int)raw.y;
      bfr[2] = (int)raw.z; bfr[3] = (int)raw.w;
      acc = __builtin_amdgcn_mfma_i32_32x32x32_i8(afr[kk], bfr, acc, 0, 0, 0);
    }
    const int col = (mc << 5) + lrow;
#pragma unroll
    for (int reg = 0; reg < 16; ++reg) {
      const int row = (strip << 5) + (reg & 3) + ((reg >> 2) << 3) +
                      (khalf << 2);
      gt[row][col] = (uint16_t)acc[reg];
    }
  }
  __syncthreads();

  // --- epilogue: stream the 64x256 att tile linearly, pair with LDS ---
  const float4* ab = (const float4*)(att + ((size_t)bc << 20) +
                                     ((size_t)lb << 8));
  float lsum = 0.f;
#pragma unroll 4
  for (int it = 0; it < 16; ++it) {
    const int idx = (it << 8) + t;        // 0..4095 float4s
    float4 av = ab[idx];
    const int row = idx >> 6, c4 = (idx & 63) << 2;
    const uint16_t* g = &gt[row][c4];
    ushort4 gv = *(const ushort4*)g;
    float d0 = fmaf((float)gv.x, -1.f / 4096.f, av.x);
    float d1 = fmaf((float)gv.y, -1.f / 4096.f, av.y);
    float d2 = fmaf((float)gv.z, -1.f / 4096.f, av.z);
    float d3 = fmaf((float)gv.w, -1.f / 4096.f, av.w);
    lsum = fmaf(d0, d0, lsum);
    lsum = fmaf(d1, d1, lsum);
    lsum = fmaf(d2, d2, lsum);
    lsum = fmaf(d3, d3, lsum);
  }

  // --- block reduction -> one atomic ---
#pragma unroll
  for (int o = 32; o > 0; o >>= 1) lsum += __shfl_down(lsum, o, 64);
  if (lane == 0) wsum[wv] = lsum;
  __syncthreads();
  if (t == 0) {
    float s = (wsum[0] + wsum[1]) + (wsum[2] + wsum[3]);
    atomicAdd(dout, s * (1.f / 33554432.f));   // / (B*C*L*L2)
  }
}

extern "C" void kernel_launch(void* const* d_in, const int* in_sizes, int n_in,
                              void* d_out, int out_size, void* d_ws, size_t ws_size,
                              hipStream_t stream) {
  (void)in_sizes; (void)n_in; (void)out_size; (void)ws_size;
  const int*   tgt = (const int*)d_in[1];     // target (int32 on device)
  const float* att = (const float*)d_in[2];   // attentions
  float* dout      = (float*)d_out;
  uint8_t* cls     = (uint8_t*)d_ws;                    // 8 MB
  uint8_t* cntT    = (uint8_t*)d_ws + (8u << 20);       // 2 MB

  prep_kernel<<<dim3(2048), BDIM, 0, stream>>>(tgt, cls, cntT, dout);
  gemm_kernel<<<dim3(64, 32), BDIM, 0, stream>>>(cls, cntT, att, dout);
}

// Round 3
// 267.896 us; speedup vs baseline: 1.0991x; 1.0991x over previous
//
#include <hip/hip_runtime.h>
#include <stdint.h>

// B=8, C=4, H=W=1024, PATCH=16, DOWN=4 -> L=4096, L2=256, K=256
// att_gt[b,c,l,m]*4096 = sum_k ind[b,c,l,k] * cnt[b,c,k,m]  (exact ints <= 4096)
// Strategy: fused prep (cls + cnt via LDS transpose) then i8 MFMA GEMM
// (M=4096,N=256,K=256 per (b,c)) with fused MSE epilogue.
// R3: B-operand (cntT panel) staged to LDS via coalesced 1KB/instr loads +
// 16B-slot XOR swizzle; B-fragments come from conflict-free ds_read_b128
// instead of 32-line global gathers (the R2 counters showed all pipes <12%
// busy -> vector-memory scatter occupancy was the stall).

#define BDIM 256

typedef int v4i  __attribute__((ext_vector_type(4)));
typedef int v16i __attribute__((ext_vector_type(16)));

// ---------------------------------------------------------------------------
// K1: fused cls + cnt (unchanged from R1 — measured fine).
// Block = one 16-row x 256-col pixel region of one image. grid.x = 2048.
// Also zeroes d_out (harness re-poisons it each launch).
// ---------------------------------------------------------------------------
__global__ __launch_bounds__(BDIM) void prep_kernel(
    const int* __restrict__ tgt, uint8_t* __restrict__ cls,
    uint8_t* __restrict__ cntT, float* __restrict__ dout) {
  __shared__ uint4 lcls[16][17];   // [row][wb], +1 pad
  const int t   = threadIdx.x;
  const int blk = blockIdx.x;
  if (blk == 0 && t == 0) *dout = 0.f;
  const int b  = blk >> 8;
  const int hr = (blk >> 2) & 63;   // h0 = hr*16
  const int wq = blk & 3;           // w0 = wq*256

  // --- read 16 target ints (one patch row), pack classes to 16 bytes ---
  {
    const int row = t >> 4, wb = t & 15;
    const int* p = tgt + ((size_t)b << 20) + ((size_t)((hr << 4) + row) << 10)
                 + (wq << 8) + (wb << 4);
    uint32_t o[4];
#pragma unroll
    for (int i = 0; i < 4; ++i) {
      int4 v = *(const int4*)(p + (i << 2));
      o[i] = (uint32_t)v.x | ((uint32_t)v.y << 8) |
             ((uint32_t)v.z << 16) | ((uint32_t)v.w << 24);
    }
    lcls[row][wb] = make_uint4(o[0], o[1], o[2], o[3]);
  }
  __syncthreads();

  // --- phase A: cls in unfold layout (transposed via LDS), coalesced ---
  {
    const int wb = t >> 4, ky = t & 15;
    const int l = (hr << 6) + (wq << 4) + wb;
    *(uint4*)(cls + ((size_t)b << 20) + ((size_t)l << 8) + (ky << 4)) =
        lcls[ky][wb];
  }

  // --- phase B: per pooled pixel (Y,X): count classes in its 4x4 block ---
  {
    const int py = t >> 6, px = t & 63;   // 4 x 64 pooled pixels in region
    uint32_t pc = 0;   // 4 packed u8 class counts (max 16 each)
#pragma unroll
    for (int dy = 0; dy < 4; ++dy) {
      uint32_t wv = ((const uint32_t*)&lcls[(py << 2) + dy][px >> 2])[px & 3];
#pragma unroll
      for (int s = 0; s < 32; s += 8)
        pc += 1u << (((wv >> s) & 3u) << 3);
    }
    const int Y = (hr << 2) + py, X = (wq << 6) + px;
    const int m  = ((Y >> 4) << 4) | (X >> 4);
    const int km = ((Y & 15) << 4) | (X & 15);
    size_t o = ((size_t)b << 18) | ((size_t)m << 8) | (size_t)km;
#pragma unroll
    for (int c = 0; c < 4; ++c)
      cntT[o + ((size_t)c << 16)] = (uint8_t)((pc >> (c << 3)) & 0xFFu);
  }
}

// ---------------------------------------------------------------------------
// K2: per (b,c): C[l][m] = sum_k ind[l][k]*cnt[k][m] via mfma_i32_32x32x32_i8,
// fused MSE vs att.
// Block = 128 l x 128 m. blockIdx.x: bit0 = m-half, bits1.. = l-tile.
// 4 waves, wave wv owns l-strip lb + wv*32, all 4 m-tiles of the half.
// cntT panel (128 m-rows x 256 k-bytes = 32 KB) staged to LDS once,
// coalesced, with 16B-slot XOR swizzle: slot = (k>>4) ^ (m'&15). Reads are
// then uniformly spread over all 8 bank-groups (minimum 8-cyc b128).
// A-frag layout: row = lane&31, k = (lane>>5)*16 + j (j = byte idx 0..15).
// B-frag layout: col = lane&31, k = (lane>>5)*16 + j.
// C/D layout:    col = lane&31, row = (reg&3) + 8*(reg>>2) + 4*(lane>>5).
// ---------------------------------------------------------------------------
__global__ __launch_bounds__(BDIM, 4) void gemm_kernel(
    const uint8_t* __restrict__ cls, const uint8_t* __restrict__ cntT,
    const float* __restrict__ att, float* __restrict__ dout) {
  __shared__ uint4 cB[2048];    // 128 rows x 16 slots of 16 B (swizzled)
  __shared__ float wsum[4];
  const int t    = threadIdx.x;
  const int wv   = t >> 6, lane = t & 63;
  const int bc   = blockIdx.y;              // 0..31 : b=bc>>2, c=bc&3
  const int b    = bc >> 2, c = bc & 3;
  const int lb   = (blockIdx.x >> 1) << 7;  // 128-l tile base
  const int mbase = (blockIdx.x & 1) << 7;  // m-half base (0 or 128)
  const int lrow  = lane & 31;
  const int khalf = lane >> 5;

  // --- stage cntT panel: 32 KB, 16-B units, fully coalesced global reads ---
  {
    const uint4* gp = (const uint4*)(cntT + ((size_t)bc << 16) + (mbase << 8));
#pragma unroll
    for (int j = 0; j < 8; ++j) {
      const int idx16 = (j << 8) + t;          // 0..2047
      const int mr    = idx16 >> 4;            // m-row 0..127
      const int slot  = (idx16 & 15) ^ (mr & 15);
      cB[(mr << 4) | slot] = gp[idx16];
    }
  }

  // --- build the 8 A fragments (k-steps of 32), kept in VGPRs ---
  // classes are < 4 (2 bits), so byte==c  <=>  both low bits of (byte^c) zero.
  // EXACT per-byte test (the classic (x-0x01..)&~x&0x80.. SWAR has borrow
  // false-positives: byte i==0 && byte i+1==0x01 flags byte i+1 — measured
  // as the round-2 absmax 1.17e-2).
  const uint32_t crep = (uint32_t)c * 0x01010101u;
  v4i afr[8];
  const uint8_t* abase = cls + ((size_t)b << 20) +
                         ((size_t)(lb + (wv << 5) + lrow) << 8) + (khalf << 4);
#pragma unroll
  for (int kk = 0; kk < 8; ++kk) {
    uint4 raw = *(const uint4*)(abase + (kk << 5));
    uint32_t r[4] = {raw.x, raw.y, raw.z, raw.w};
    v4i a;
#pragma unroll
    for (int i = 0; i < 4; ++i) {
      uint32_t x = r[i] ^ crep;                        // 0 where byte==c
      uint32_t nz = (x | (x >> 1)) & 0x01010101u;      // 1 where byte!=c
      a[i] = (int)(nz ^ 0x01010101u);                  // 1 where byte==c
    }
    afr[kk] = a;
  }

  __syncthreads();   // cB ready

  // att fragment base: row = lb + wv*32 + khalf*4 (+ (reg&3) + 8*(reg>>2)),
  //                    col = mbase + mc*32 + lrow
  const float* attbase = att + ((size_t)bc << 20) +
                         ((size_t)(lb + (wv << 5) + (khalf << 2)) << 8) +
                         mbase + lrow;
  float ls[4] = {0.f, 0.f, 0.f, 0.f};

#pragma unroll
  for (int mc = 0; mc < 4; ++mc) {
    const float* ap = attbase + (mc << 5);
    float av[16];
#pragma unroll
    for (int reg = 0; reg < 16; ++reg)
      av[reg] = ap[((reg & 3) << 8) + ((reg >> 2) << 11)];

    const int mr = (mc << 5) + lrow;           // LDS m-row for this lane
    v16i acc = {0,0,0,0,0,0,0,0,0,0,0,0,0,0,0,0};
#pragma unroll
    for (int kk = 0; kk < 8; ++kk) {
      const int slot = ((kk << 1) + khalf) ^ (mr & 15);
      uint4 raw = cB[(mr << 4) | slot];
      v4i bfr;
      bfr[0] = (int)raw.x; bfr[1] = (int)raw.y;
      bfr[2] = (int)raw.z; bfr[3] = (int)raw.w;
      acc = __builtin_amdgcn_mfma_i32_32x32x32_i8(afr[kk], bfr, acc, 0, 0, 0);
    }
#pragma unroll
    for (int reg = 0; reg < 16; ++reg) {
      float d = fmaf((float)acc[reg], -1.f / 4096.f, av[reg]);
      ls[reg & 3] = fmaf(d, d, ls[reg & 3]);
    }
  }

  // --- block reduction -> one atomic ---
  float lsum = (ls[0] + ls[1]) + (ls[2] + ls[3]);
#pragma unroll
  for (int o = 32; o > 0; o >>= 1) lsum += __shfl_down(lsum, o, 64);
  if (lane == 0) wsum[wv] = lsum;
  __syncthreads();
  if (t == 0) {
    float s = (wsum[0] + wsum[1]) + (wsum[2] + wsum[3]);
    atomicAdd(dout, s * (1.f / 33554432.f));   // / (B*C*L*L2)
  }
}

extern "C" void kernel_launch(void* const* d_in, const int* in_sizes, int n_in,
                              void* d_out, int out_size, void* d_ws, size_t ws_size,
                              hipStream_t stream) {
  (void)in_sizes; (void)n_in; (void)out_size; (void)ws_size;
  const int*   tgt = (const int*)d_in[1];     // target (int32 on device)
  const float* att = (const float*)d_in[2];   // attentions
  float* dout      = (float*)d_out;
  uint8_t* cls     = (uint8_t*)d_ws;                    // 8 MB
  uint8_t* cntT    = (uint8_t*)d_ws + (8u << 20);       // 2 MB

  prep_kernel<<<dim3(2048), BDIM, 0, stream>>>(tgt, cls, cntT, dout);
  gemm_kernel<<<dim3(64, 32), BDIM, 0, stream>>>(cls, cntT, att, dout);
}